// Round 1
// baseline (19.103 us; speedup 1.0000x reference)
//
#include <hip/hip_runtime.h>
#include <math.h>

// ---------------------------------------------------------------------------
// TripletLossAttribute:
//   w[i,j,k] = attr[i,j,seg(k)], seg boundaries at 341*d (last segment 343)
//   sq[i,j]  = sum_k (w*(x_j[k]-x_i[k]))^2 = sum_k a2[seg(k)]*(dx)^2
//   dist     = sqrt(clip(sq, 1e-12))
//   ap[i] = max_{t_j==t_i} dist[i,j];  an[i] = min_{t_j!=t_i} dist[i,j]
//   loss = mean(relu(ap - an + 0.3))
// ---------------------------------------------------------------------------

// One wave (64 lanes) per (i,j) pair. 4096 blocks of 64 threads.
__global__ __launch_bounds__(64) void pair_dist_kernel(
    const float* __restrict__ x,     // 64 x 2048
    const float* __restrict__ attr,  // 64 x 64 x 6
    float* __restrict__ dist)        // 64 x 64
{
    const int pair = blockIdx.x;     // i*64 + j
    const int i    = pair >> 6;
    const int j    = pair & 63;
    const int lane = threadIdx.x;    // 0..63

    const float4* __restrict__ xi = (const float4*)(x + i * 2048);
    const float4* __restrict__ xj = (const float4*)(x + j * 2048);
    const float*  __restrict__ a  = attr + pair * 6;

    // squared attention weights for the 6 segments (named scalars: no
    // runtime-indexed array -> stays in VGPRs)
    const float a20 = a[0] * a[0];
    const float a21 = a[1] * a[1];
    const float a22 = a[2] * a[2];
    const float a23 = a[3] * a[3];
    const float a24 = a[4] * a[4];
    const float a25 = a[5] * a[5];

    float acc = 0.f;

#define ACC_COMP(K, DX)                                                      \
    {                                                                        \
        unsigned kk = (unsigned)(K);                                         \
        unsigned d  = kk / 341u;                                             \
        d = d > 5u ? 5u : d;  /* k=2046,2047 fall in segment 5 */            \
        float dx = (DX);                                                     \
        float w2 = (d == 0u) ? a20                                           \
                 : (d == 1u) ? a21                                           \
                 : (d == 2u) ? a22                                           \
                 : (d == 3u) ? a23                                           \
                 : (d == 4u) ? a24 : a25;                                    \
        acc = fmaf(dx * dx, w2, acc);                                        \
    }

#pragma unroll
    for (int t = 0; t < 8; ++t) {
        int c = t * 64 + lane;       // float4 chunk, 0..511 (coalesced)
        float4 vi = xi[c];
        float4 vj = xj[c];
        int k0 = c * 4;
        ACC_COMP(k0 + 0, vj.x - vi.x);
        ACC_COMP(k0 + 1, vj.y - vi.y);
        ACC_COMP(k0 + 2, vj.z - vi.z);
        ACC_COMP(k0 + 3, vj.w - vi.w);
    }
#undef ACC_COMP

    // wave-wide sum (64 lanes)
#pragma unroll
    for (int off = 32; off; off >>= 1) acc += __shfl_xor(acc, off);

    if (lane == 0) dist[pair] = sqrtf(fmaxf(acc, 1e-12f));
}

// Single block: per-row masked max/min + mean of relu terms.
__global__ __launch_bounds__(256) void loss_kernel(
    const float* __restrict__ dist,  // 64 x 64
    const int*   __restrict__ tgt,   // 64
    float*       __restrict__ out)   // 1
{
    __shared__ float terms[64];
    const int lane = threadIdx.x & 63;
    const int wave = threadIdx.x >> 6;   // 0..3

    const int tl = tgt[lane];            // target of column `lane`

    for (int r = wave; r < 64; r += 4) {
        const int tr = tgt[r];
        float dj = dist[r * 64 + lane];
        bool pos = (tr == tl);
        float ap = pos ? dj : -INFINITY;
        float an = pos ? INFINITY : dj;
#pragma unroll
        for (int off = 32; off; off >>= 1) {
            ap = fmaxf(ap, __shfl_xor(ap, off));
            an = fminf(an, __shfl_xor(an, off));
        }
        if (lane == 0) terms[r] = fmaxf(ap - an + 0.3f, 0.f);
    }
    __syncthreads();

    if (threadIdx.x < 64) {
        float v = terms[threadIdx.x];
#pragma unroll
        for (int off = 32; off; off >>= 1) v += __shfl_xor(v, off);
        if (threadIdx.x == 0) out[0] = v * (1.0f / 64.0f);
    }
}

extern "C" void kernel_launch(void* const* d_in, const int* in_sizes, int n_in,
                              void* d_out, int out_size, void* d_ws, size_t ws_size,
                              hipStream_t stream) {
    const float* x    = (const float*)d_in[0];   // inputs (64,2048) f32
    const int*   tgt  = (const int*)d_in[1];     // targets (64,) i32
    const float* attr = (const float*)d_in[2];   // attention (64,64,6) f32
    float* out  = (float*)d_out;
    float* dist = (float*)d_ws;                  // 4096 floats scratch

    pair_dist_kernel<<<4096, 64, 0, stream>>>(x, attr, dist);
    loss_kernel<<<1, 256, 0, stream>>>(dist, tgt, out);
}

// Round 2
// 13.543 us; speedup vs baseline: 1.4105x; 1.4105x over previous
//
#include <hip/hip_runtime.h>
#include <math.h>

// ---------------------------------------------------------------------------
// TripletLossAttribute:
//   seg(k): k in [341*d, 341*(d+1)) for d<5, seg5 = [1705, 2048)
//   sq[i,j]  = sum_k a2[i,j,seg(k)] * (x_j[k]-x_i[k])^2
//   dist     = sqrt(max(sq, 1e-12))
//   ap[i] = max_{t_j==t_i} dist[i,j];  an[i] = min_{t_j!=t_i} dist[i,j]
//   loss = mean(relu(ap - an + 0.3))
//
// Segment-select trick: with the 8-step t-loop unrolled, step t covers
// k in [t*256, t*256+256), which crosses AT MOST ONE segment boundary
// (boundaries 341,682,1023,1364,1705). So per element the weight select is
// one compare against a compile-time constant (none at all for t=0,4,7).
// ---------------------------------------------------------------------------

// 4 waves/block, one (i,j) pair per wave. 1024 blocks x 256 threads.
__global__ __launch_bounds__(256) void pair_dist_kernel(
    const float* __restrict__ x,     // 64 x 2048
    const float* __restrict__ attr,  // 64 x 64 x 6
    float* __restrict__ dist)        // 64 x 64
{
    const int wid  = blockIdx.x * 4 + (threadIdx.x >> 6);  // pair = i*64+j
    const int lane = threadIdx.x & 63;
    const int i    = wid >> 6;
    const int j    = wid & 63;

    const float4* __restrict__ xi = (const float4*)(x + i * 2048);
    const float4* __restrict__ xj = (const float4*)(x + j * 2048);
    const float*  __restrict__ a  = attr + wid * 6;

    // squared attention weights (named scalars -> VGPRs, no scratch)
    const float a20 = a[0] * a[0];
    const float a21 = a[1] * a[1];
    const float a22 = a[2] * a[2];
    const float a23 = a[3] * a[3];
    const float a24 = a[4] * a[4];
    const float a25 = a[5] * a[5];

    float acc = 0.f;

    // step with one boundary B inside [T*256, T*256+256): w2 = k<B ? WLO : WHI
#define STEP_B(T, WLO, WHI, B)                                               \
    {                                                                        \
        const int c  = (T) * 64 + lane;                                      \
        const int k0 = c * 4;                                                \
        float4 vi = xi[c];                                                   \
        float4 vj = xj[c];                                                   \
        float dx;                                                            \
        dx = vj.x - vi.x; acc = fmaf(dx * dx, (k0 + 0 < (B)) ? (WLO) : (WHI), acc); \
        dx = vj.y - vi.y; acc = fmaf(dx * dx, (k0 + 1 < (B)) ? (WLO) : (WHI), acc); \
        dx = vj.z - vi.z; acc = fmaf(dx * dx, (k0 + 2 < (B)) ? (WLO) : (WHI), acc); \
        dx = vj.w - vi.w; acc = fmaf(dx * dx, (k0 + 3 < (B)) ? (WLO) : (WHI), acc); \
    }
    // step entirely inside one segment: no select at all
#define STEP_U(T, W)                                                         \
    {                                                                        \
        const int c = (T) * 64 + lane;                                       \
        float4 vi = xi[c];                                                   \
        float4 vj = xj[c];                                                   \
        float dx;                                                            \
        dx = vj.x - vi.x; acc = fmaf(dx * dx, (W), acc);                     \
        dx = vj.y - vi.y; acc = fmaf(dx * dx, (W), acc);                     \
        dx = vj.z - vi.z; acc = fmaf(dx * dx, (W), acc);                     \
        dx = vj.w - vi.w; acc = fmaf(dx * dx, (W), acc);                     \
    }

    STEP_U(0, a20);                 // k in [0,256)      : seg0
    STEP_B(1, a20, a21, 341);       // k in [256,512)    : seg0|seg1
    STEP_B(2, a21, a22, 682);       // k in [512,768)    : seg1|seg2
    STEP_B(3, a22, a23, 1023);      // k in [768,1024)   : seg2|seg3
    STEP_U(4, a23);                 // k in [1024,1280)  : seg3
    STEP_B(5, a23, a24, 1364);      // k in [1280,1536)  : seg3|seg4
    STEP_B(6, a24, a25, 1705);      // k in [1536,1792)  : seg4|seg5
    STEP_U(7, a25);                 // k in [1792,2048)  : seg5
#undef STEP_B
#undef STEP_U

    // wave-wide sum (64 lanes)
#pragma unroll
    for (int off = 32; off; off >>= 1) acc += __shfl_xor(acc, off);

    if (lane == 0) dist[wid] = sqrtf(fmaxf(acc, 1e-12f));
}

// 16 waves; each wave does 4 rows (loads issued up-front), then wave 0 means.
__global__ __launch_bounds__(1024) void loss_kernel(
    const float* __restrict__ dist,  // 64 x 64
    const int*   __restrict__ tgt,   // 64
    float*       __restrict__ out)   // 1
{
    __shared__ float terms[64];
    const int lane = threadIdx.x & 63;
    const int wave = threadIdx.x >> 6;   // 0..15
    const int r0   = wave * 4;

    const int tl = tgt[lane];            // target of column `lane`

    // issue all 4 row loads before consuming (hide L2 latency)
    float d0 = dist[(r0 + 0) * 64 + lane];
    float d1 = dist[(r0 + 1) * 64 + lane];
    float d2 = dist[(r0 + 2) * 64 + lane];
    float d3 = dist[(r0 + 3) * 64 + lane];

#define ROW_REDUCE(RR, DV)                                                   \
    {                                                                        \
        const int tr = tgt[RR];                                              \
        bool pos = (tr == tl);                                               \
        float ap = pos ? (DV) : -INFINITY;                                   \
        float an = pos ? INFINITY : (DV);                                    \
        _Pragma("unroll")                                                    \
        for (int off = 32; off; off >>= 1) {                                 \
            ap = fmaxf(ap, __shfl_xor(ap, off));                             \
            an = fminf(an, __shfl_xor(an, off));                             \
        }                                                                    \
        if (lane == 0) terms[RR] = fmaxf(ap - an + 0.3f, 0.f);               \
    }
    ROW_REDUCE(r0 + 0, d0);
    ROW_REDUCE(r0 + 1, d1);
    ROW_REDUCE(r0 + 2, d2);
    ROW_REDUCE(r0 + 3, d3);
#undef ROW_REDUCE

    __syncthreads();

    if (threadIdx.x < 64) {
        float v = terms[threadIdx.x];
#pragma unroll
        for (int off = 32; off; off >>= 1) v += __shfl_xor(v, off);
        if (threadIdx.x == 0) out[0] = v * (1.0f / 64.0f);
    }
}

extern "C" void kernel_launch(void* const* d_in, const int* in_sizes, int n_in,
                              void* d_out, int out_size, void* d_ws, size_t ws_size,
                              hipStream_t stream) {
    const float* x    = (const float*)d_in[0];   // inputs (64,2048) f32
    const int*   tgt  = (const int*)d_in[1];     // targets (64,) i32
    const float* attr = (const float*)d_in[2];   // attention (64,64,6) f32
    float* out  = (float*)d_out;
    float* dist = (float*)d_ws;                  // 4096 floats scratch

    pair_dist_kernel<<<1024, 256, 0, stream>>>(x, attr, dist);
    loss_kernel<<<1, 1024, 0, stream>>>(dist, tgt, out);
}